// Round 10
// baseline (495.325 us; speedup 1.0000x reference)
//
#include <hip/hip_runtime.h>

// Problem constants
#define DMODEL 1024
#define NHEADS 16
#define HDIM   64
#define SEQ    2048
#define BATCH  2
#define MROWS  (SEQ*BATCH)   // 4096

typedef unsigned int u32;
typedef unsigned short u16;
typedef __attribute__((ext_vector_type(8))) short bfrag;    // 8 bf16 (A/B frag)
typedef __attribute__((ext_vector_type(4))) float f32x4;    // 16x16 C/D frag
typedef __attribute__((ext_vector_type(16))) float f32x16;  // 32x32 C/D frag
typedef union { u32 u[4]; bfrag f; } fragu;

// bf16 split helpers (RTN-even hi). x ~= hi + lo
__device__ __forceinline__ u32 f2bf(float x) {
    unsigned u = __float_as_uint(x);
    return (u + 0x7fffu + ((u >> 16) & 1u)) >> 16;
}
__device__ __forceinline__ float bf2f(u32 h) {
    return __uint_as_float(h << 16);
}

// async global->LDS, 16B/lane; LDS dest = wave-uniform base (+lane*16 by HW)
__device__ __forceinline__ void gld16(const void* g, void* l) {
    __builtin_amdgcn_global_load_lds(
        (const __attribute__((address_space(1))) unsigned int*)g,
        (__attribute__((address_space(3))) unsigned int*)l, 16, 0, 0);
}

// ---------------------------------------------------------------------------
// BLOCKED hi/lo format: each row of 1024 elems = 32 groups of 32; group t
// occupies 64 u16: [32 hi][32 lo]. Same bytes as fp32, frag reads need no
// unpack VALU (hi chunk = lquad, lo chunk = 4+lquad within the 128B group).
// ---------------------------------------------------------------------------

// Prep:
//  y=0..2 : Wq/Wk/Wv -> blocked hi/lo into ws              (512 blocks, 8/thr)
//  y=3    : f64-accurate RoPE table                         (256 blocks)
//  y=4..6 : query/key/value packed IN PLACE to blocked      (512 blocks, 32/thr
//           = one full 128B group per thread -> race-free in place)
__global__ __launch_bounds__(256) void prep_kernel(
    const float* __restrict__ Wq, const float* __restrict__ Wk,
    const float* __restrict__ Wv,
    float* __restrict__ query, float* __restrict__ key, float* __restrict__ value,
    u16* __restrict__ wqb, u16* __restrict__ wkb, u16* __restrict__ wvb,
    float2* __restrict__ tab)
{
    const int y = blockIdx.y;
    if (y == 3) {
        if (blockIdx.x >= 256) return;
        const int e = blockIdx.x * 256 + threadIdx.x;   // 65536 = 2048 s x 32 i
        const int s = e >> 5, i = e & 31;
        const double th = exp(-(double)i * (9.210340371976184 / 32.0)); // ln(1e4)/32
        double sn, cs;
        sincos((double)s * th, &sn, &cs);
        tab[e] = make_float2((float)sn, (float)cs);
        return;
    }
    if (y < 3) {
        const float* src = (y == 0) ? Wq : (y == 1) ? Wk : Wv;
        u16* dst = (y == 0) ? wqb : (y == 1) ? wkb : wvb;
        const int i = blockIdx.x * 256 + threadIdx.x;   // 8 elems/thread
        const int e0  = i * 8;
        const int row = e0 >> 10, k = e0 & 1023, t = k >> 5, j0 = k & 31;
        float xs[8];
        *(float4*)&xs[0] = ((const float4*)src)[i * 2];
        *(float4*)&xs[4] = ((const float4*)src)[i * 2 + 1];
        __align__(16) u16 hb[8];
        __align__(16) u16 lb[8];
        #pragma unroll
        for (int j = 0; j < 8; ++j) {
            const u32 h = f2bf(xs[j]);
            hb[j] = (u16)h;
            lb[j] = (u16)f2bf(xs[j] - bf2f(h));
        }
        u16* o = dst + (size_t)row * 2048 + t * 64 + j0;
        *(uint4*)o        = *(const uint4*)hb;
        *(uint4*)(o + 32) = *(const uint4*)lb;
        return;
    }
    // in-place input pack: one 128B group (32 elems) per thread
    float* io = (y == 4) ? query : (y == 5) ? key : value;
    const int gi = blockIdx.x * 256 + threadIdx.x;      // 0..131071
    uint4* io4 = (uint4*)io + (size_t)gi * 8;
    uint4 raw[8];
    #pragma unroll
    for (int j = 0; j < 8; ++j) raw[j] = io4[j];
    __align__(16) u16 hb[32];
    __align__(16) u16 lb[32];
    #pragma unroll
    for (int j = 0; j < 32; ++j) {
        const float x = __uint_as_float(((const u32*)raw)[j]);
        const u32 h = f2bf(x);
        hb[j] = (u16)h;
        lb[j] = (u16)f2bf(x - bf2f(h));
    }
    #pragma unroll
    for (int j = 0; j < 4; ++j) io4[j]     = ((const uint4*)hb)[j];
    #pragma unroll
    for (int j = 0; j < 4; ++j) io4[4 + j] = ((const uint4*)lb)[j];
}

// pack Wo -> blocked (runs after attn frees its ws slot)
__global__ __launch_bounds__(256) void pack_kernel(
    const float* __restrict__ src, u16* __restrict__ dst)
{
    const int i = blockIdx.x * 256 + threadIdx.x;
    const int e0  = i * 8;
    const int row = e0 >> 10, k = e0 & 1023, t = k >> 5, j0 = k & 31;
    float xs[8];
    *(float4*)&xs[0] = ((const float4*)src)[i * 2];
    *(float4*)&xs[4] = ((const float4*)src)[i * 2 + 1];
    __align__(16) u16 hb[8];
    __align__(16) u16 lb[8];
    #pragma unroll
    for (int j = 0; j < 8; ++j) {
        const u32 h = f2bf(xs[j]);
        hb[j] = (u16)h;
        lb[j] = (u16)f2bf(xs[j] - bf2f(h));
    }
    u16* o = dst + (size_t)row * 2048 + t * 64 + j0;
    *(uint4*)o        = *(const uint4*)hb;
    *(uint4*)(o + 32) = *(const uint4*)lb;
}

// zero AOf (16MB) and lsum (256KB) before attn's atomic accumulation
__global__ __launch_bounds__(256) void zero_kernel(float* __restrict__ AOf,
                                                   float* __restrict__ lsum)
{
    const int y = blockIdx.y;
    uint4* dst  = (uint4*)(y == 0 ? AOf : lsum);
    const int n = (y == 0) ? (1 << 20) : (1 << 14);
    const int i = blockIdx.x * 256 + threadIdx.x;
    if (i < n) dst[i] = make_uint4(0, 0, 0, 0);
}

// ---------------------------------------------------------------------------
// Pipelined split-bf16 MFMA GEMM body, BLOCKED hi/lo operands (no unpack).
// BM=128, BN=NI*16; K in 32-wide half-steps, single barrier per step.
// LDS: sA 2x128x64 u16 = 32KB, sB 2x(NI*16)x64 u16 (16KB @ NI=4, 8KB @ NI=2).
// mode 0 (NI=4): RoPE(+scale)+split -> [b][h][s][d] bf16 hi/lo (Q/K)
// mode 1 (NI=4): bf16-hi, transposed + key-quartet-permuted -> V^T
// mode 2: fp32 row-major Mx1024
// ---------------------------------------------------------------------------
template <int NI>
__device__ __forceinline__ void gemm_body(
    int id, int mode,
    const u16* __restrict__ Ab, const u16* __restrict__ Wb,
    const float* __restrict__ bias, const float2* __restrict__ tab,
    float rope_scale,
    u16* __restrict__ Oh, u16* __restrict__ Ol, float* __restrict__ Of,
    u16* smem16)
{
    u16* sA = smem16;               // 2 halves x 128 rows x 64 u16
    u16* sB = smem16 + 16384;       // 2 halves x (NI*16) rows x 64 u16

    const int tid   = threadIdx.x;
    const int w     = tid >> 6;
    const int lane  = tid & 63;
    const int lrow  = lane & 15;
    const int lquad = lane >> 4;

    // XCD-aware remap (id%8 ~ XCD; per XCD 4 m-tiles x all n-tiles)
    const int NBLK = 1024 / (NI * 16);
    const int xcd  = id & 7;
    const int jj   = id >> 3;
    const int nblk = jj & (NBLK - 1);
    const int mblk = (xcd << 2) | (jj / NBLK);
    const int n0   = nblk * NI * 16;
    const int m0   = mblk * 128;

    // staging coords: 8-row slabs, 8 chunks of 16B per 128B row-group
    const int srow8 = lane >> 3;
    const int sch   = (lane & 7) ^ srow8;

    // frag offsets (u16 units): hi chunk = lquad, lo chunk = 4+lquad
    int aoffh[2], aoffl[2], boffh[NI], boffl[NI];
    #pragma unroll
    for (int mi = 0; mi < 2; ++mi) {
        const int ra = w * 32 + mi * 16 + lrow;
        aoffh[mi] = ra * 64 + ((lquad ^ (ra & 7)) << 3);
        aoffl[mi] = ra * 64 + (((lquad + 4) ^ (ra & 7)) << 3);
    }
    #pragma unroll
    for (int ni = 0; ni < NI; ++ni) {
        const int rb = ni * 16 + lrow;
        boffh[ni] = rb * 64 + ((lquad ^ (rb & 7)) << 3);
        boffl[ni] = rb * 64 + (((lquad + 4) ^ (rb & 7)) << 3);
    }

    f32x4 acc[2][NI] = {};

    auto stage = [&](int t) {
        const int h = t & 1;
        #pragma unroll
        for (int i = 0; i < 4; ++i) {          // A: 16 gld16 total
            const int slab = w * 4 + i;
            const int row  = slab * 8 + srow8;
            gld16(Ab + (size_t)(m0 + row) * 2048 + t * 64 + sch * 8,
                  sA + h * 8192 + slab * 512);
        }
        #pragma unroll
        for (int i = 0; i < NI / 2; ++i) {     // B: 2*NI gld16 total
            const int slab = w * (NI / 2) + i;
            const int row  = slab * 8 + srow8;
            gld16(Wb + (size_t)(n0 + row) * 2048 + t * 64 + sch * 8,
                  sB + h * (NI * 1024) + slab * 512);
        }
    };

    stage(0);
    for (int t = 0; t < 32; ++t) {
        __syncthreads();                       // half t ready (vmcnt drained)
        if (t < 31) stage(t + 1);
        const int h = t & 1;
        const u16* sAh_ = sA + h * 8192;
        const u16* sBh_ = sB + h * (NI * 1024);

        bfrag ah[2], al[2], bh[NI], bl[NI];
        #pragma unroll
        for (int mi = 0; mi < 2; ++mi) {
            ah[mi] = *(const bfrag*)&sAh_[aoffh[mi]];
            al[mi] = *(const bfrag*)&sAh_[aoffl[mi]];
        }
        #pragma unroll
        for (int ni = 0; ni < NI; ++ni) {
            bh[ni] = *(const bfrag*)&sBh_[boffh[ni]];
            bl[ni] = *(const bfrag*)&sBh_[boffl[ni]];
        }

        #pragma unroll
        for (int mi = 0; mi < 2; ++mi)
            #pragma unroll
            for (int ni = 0; ni < NI; ++ni) {
                acc[mi][ni] = __builtin_amdgcn_mfma_f32_16x16x32_bf16(ah[mi], bh[ni], acc[mi][ni], 0, 0, 0);
                acc[mi][ni] = __builtin_amdgcn_mfma_f32_16x16x32_bf16(ah[mi], bl[ni], acc[mi][ni], 0, 0, 0);
                acc[mi][ni] = __builtin_amdgcn_mfma_f32_16x16x32_bf16(al[mi], bh[ni], acc[mi][ni], 0, 0, 0);
            }
    }

    float bn[NI];
    #pragma unroll
    for (int ni = 0; ni < NI; ++ni) bn[ni] = bias[n0 + ni * 16 + lrow];

    if constexpr (NI == 4) {
        if (mode == 0) {
            const int hblk = nblk;
            #pragma unroll
            for (int mi = 0; mi < 2; ++mi)
                #pragma unroll
                for (int r = 0; r < 4; ++r) {
                    const int mrow = w * 32 + mi * 16 + lquad * 4 + r;
                    const int m  = m0 + mrow;
                    const int bb = m & 1;
                    const int sg = m >> 1;
                    const size_t ob = (((size_t)(bb * NHEADS + hblk) * SEQ) + sg) * HDIM;
                    #pragma unroll
                    for (int ni = 0; ni < 2; ++ni) {
                        const int i = ni * 16 + lrow;
                        const float2 sc = tab[(size_t)sg * 32 + i];
                        const float x1 = acc[mi][ni][r]     + bn[ni];
                        const float x2 = acc[mi][ni + 2][r] + bn[ni + 2];
                        // reference quirk: o2 = x1*sin - x2*cos
                        const float o1 = (x1 * sc.y - x2 * sc.x) * rope_scale;
                        const float o2 = (x1 * sc.x - x2 * sc.y) * rope_scale;
                        const u32 h1 = f2bf(o1);
                        const u32 h2 = f2bf(o2);
                        Oh[ob + i]      = (u16)h1;  Ol[ob + i]      = (u16)f2bf(o1 - bf2f(h1));
                        Oh[ob + i + 32] = (u16)h2;  Ol[ob + i + 32] = (u16)f2bf(o2 - bf2f(h2));
                    }
                }
            return;
        }
        if (mode == 1) {
            // bf16-hi V^T, transposed via LDS (stride 65), key-quartet permuted
            __syncthreads();
            u32* vb = (u32*)smem16;    // 8320 u32 <= 48KB
            #pragma unroll
            for (int mi = 0; mi < 2; ++mi)
                #pragma unroll
                for (int r = 0; r < 4; ++r) {
                    const int mrow = w * 32 + mi * 16 + lquad * 4 + r;
                    const int bb = mrow & 1;
                    const int sl = mrow >> 1;
                    #pragma unroll
                    for (int ni = 0; ni < 4; ++ni) {
                        const int d = ni * 16 + lrow;
                        vb[bb * 4160 + d * 65 + sl] = f2bf(acc[mi][ni][r] + bn[ni]);
                    }
                }
            __syncthreads();
            const int hblk = nblk;
            #pragma unroll
            for (int rep = 0; rep < 4; ++rep) {
                const int c  = rep * 256 + tid;      // 1024 chunks
                const int bb = c >> 9;
                const int d  = (c >> 3) & 63;
                const int s8 = c & 7;
                __align__(8) u16 hb[8];
                #pragma unroll
                for (int j = 0; j < 8; ++j)
                    hb[j] = (u16)vb[bb * 4160 + d * 65 + s8 * 8 + j];
                const size_t orow = ((size_t)(bb * NHEADS + hblk) * HDIM + d) * SEQ + (m0 >> 1);
                const int blk16 = (s8 >> 1) * 16;
                const int off   = (s8 & 1) * 4;
                *(uint2*)&Oh[orow + blk16 + off]     = *(const uint2*)&hb[0];
                *(uint2*)&Oh[orow + blk16 + 8 + off] = *(const uint2*)&hb[4];
            }
            return;
        }
    }
    // mode 2: fp32 row-major
    #pragma unroll
    for (int mi = 0; mi < 2; ++mi)
        #pragma unroll
        for (int r = 0; r < 4; ++r) {
            const int m = m0 + w * 32 + mi * 16 + lquad * 4 + r;
            #pragma unroll
            for (int ni = 0; ni < NI; ++ni)
                Of[(size_t)m * 1024 + n0 + ni * 16 + lrow] = acc[mi][ni][r] + bn[ni];
        }
}

// Merged Q/K/V projection: blockIdx.z selects projection (0=Q,1=K,2=V).
__global__ __launch_bounds__(256) void qkv_gemm_kernel(
    const u16* __restrict__ query, const u16* __restrict__ key,
    const u16* __restrict__ value,
    const u16* __restrict__ Wqb, const u16* __restrict__ Wkb,
    const u16* __restrict__ Wvb,
    const float* __restrict__ bq, const float* __restrict__ bk,
    const float* __restrict__ bv, const float2* __restrict__ tab,
    u16* __restrict__ Qh, u16* __restrict__ Ql,
    u16* __restrict__ Kh, u16* __restrict__ Kl,
    u16* __restrict__ VTh)
{
    __shared__ u16 smem16[24576];                 // 48 KB
    const int z  = blockIdx.z;
    const int id = blockIdx.x + 16 * blockIdx.y;
    const u16* A    = (z == 0) ? query : (z == 1) ? key : value;
    const u16* Wb   = (z == 0) ? Wqb : (z == 1) ? Wkb : Wvb;
    const float* bb = (z == 0) ? bq : (z == 1) ? bk : bv;
    u16* Oh = (z == 0) ? Qh : (z == 1) ? Kh : VTh;
    u16* Ol = (z == 0) ? Ql : (z == 1) ? Kl : nullptr;
    const int mode = (z == 2) ? 1 : 0;
    const float scale = (z == 0) ? 0.125f : 1.0f;
    gemm_body<4>(id, mode, A, Wb, bb, tab, scale, Oh, Ol, nullptr, smem16);
}

// Final projection: A = combined attn output (blocked), BN=32, grid 1024.
__global__ __launch_bounds__(256) void out_gemm_kernel(
    const u16* __restrict__ Ab, const u16* __restrict__ Wb,
    const float* __restrict__ bias, float* __restrict__ Of)
{
    __shared__ u16 smem16[20480];                 // 40 KB
    const int id = blockIdx.x + 32 * blockIdx.y;
    gemm_body<2>(id, 2, Ab, Wb, bias, nullptr, 1.0f, nullptr, nullptr, Of, smem16);
}

// ---------------------------------------------------------------------------
// MFMA flash attention, SPLIT-K x2 (blockIdx.z = key-half), 32x32x16,
// no-max softmax, S^T/O^T, register-P, no-exchange (permuted V^T), P/V hi-only.
// Single-buffer 24KB LDS -> 4 blocks/CU (16 waves/CU, 2x R9's hiding).
// Partials accumulated with fp32 atomicAdd (exactly 2 commutative adds per
// element after zero_kernel -> bit-deterministic).
// ---------------------------------------------------------------------------
__global__ __launch_bounds__(256) void attn_mfma_kernel(
    const u16* __restrict__ Qh, const u16* __restrict__ Ql,
    const u16* __restrict__ Kh, const u16* __restrict__ Kl,
    const u16* __restrict__ Vh,
    float* __restrict__ AOf, float* __restrict__ lsum)
{
    __shared__ u16 sKh[4096], sKl[4096], sVh[4096];   // 24 KB

    const int tid  = threadIdx.x;
    const int w    = tid >> 6;             // 0..3
    const int lane = tid & 63;
    const int l31  = lane & 31;
    const int g    = lane >> 5;

    const int id = blockIdx.x + 16 * blockIdx.y;   // 0..511
    const int jj = id >> 3;
    const int bh = ((id & 7) << 2) | (jj >> 4);
    const int qt = jj & 15;
    const int kh = blockIdx.z;                     // key half

    // Q B-frags (registers): col=q=l31, k = ks*16 + g*8 + j
    const size_t qg = ((size_t)bh * SEQ + qt * 128 + w * 32 + l31) * HDIM + g * 8;
    bfrag qfh[4], qfl[4];
    #pragma unroll
    for (int ks = 0; ks < 4; ++ks) {
        qfh[ks] = *(const bfrag*)&Qh[qg + ks * 16];
        qfl[ks] = *(const bfrag*)&Ql[qg + ks * 16];
    }

    // staging: wave 0->sKh, 1->sKl, 2->sVh, 3 idle; 8 gld16 x 1KB each
    const int srow   = lane >> 3;
    const int schunk = (lane & 7) ^ srow;
    const u16* gsrc = nullptr; u16* lbase = nullptr; size_t istep = 0, ktstep = 0;
    if (w == 0) {
        gsrc = Kh + ((size_t)bh * SEQ + srow) * HDIM + schunk * 8;
        istep = 8 * 64; ktstep = 64 * 64; lbase = sKh;
    } else if (w == 1) {
        gsrc = Kl + ((size_t)bh * SEQ + srow) * HDIM + schunk * 8;
        istep = 8 * 64; ktstep = 64 * 64; lbase = sKl;
    } else if (w == 2) {
        gsrc = Vh + ((size_t)bh * HDIM + srow) * SEQ + schunk * 8;
        istep = 8 * SEQ; ktstep = 64; lbase = sVh;
    }

    int koff[2][4];
    #pragma unroll
    for (int a = 0; a < 2; ++a) {
        const int row = a * 32 + l31;
        #pragma unroll
        for (int c = 0; c < 4; ++c)
            koff[a][c] = row * 64 + (((c * 2 + g) ^ (row & 7)) << 3);
    }

    f32x16 accO[2] = {};
    float l_loc = 0.0f;

    for (int kt = kh * 16; kt < kh * 16 + 16; ++kt) {
        __syncthreads();                     // prior compute's LDS reads done
        if (w < 3) {
            const u16* gp = gsrc + (size_t)kt * ktstep;
            #pragma unroll
            for (int i = 0; i < 8; ++i)
                gld16(gp + (size_t)i * istep, lbase + i * 512);
        }
        __syncthreads();                     // staging drained (vmcnt)

        // ---- S^T = K Q^T (Q pre-scaled) : lane=q, regs=keys ----
        f32x16 accS[2] = {};
        #pragma unroll
        for (int kg = 0; kg < 2; ++kg)
            #pragma unroll
            for (int ks = 0; ks < 4; ++ks) {
                const bfrag kh_ = *(const bfrag*)&sKh[koff[kg][ks]];
                const bfrag kl_ = *(const bfrag*)&sKl[koff[kg][ks]];
                accS[kg] = __builtin_amdgcn_mfma_f32_32x32x16_bf16(kh_, qfh[ks], accS[kg], 0, 0, 0);
                accS[kg] = __builtin_amdgcn_mfma_f32_32x32x16_bf16(kh_, qfl[ks], accS[kg], 0, 0, 0);
                accS[kg] = __builtin_amdgcn_mfma_f32_32x32x16_bf16(kl_, qfh[ks], accS[kg], 0, 0, 0);
            }

        // ---- p = exp(s) in registers ----
        float pv[2][16];
        #pragma unroll
        for (int kg = 0; kg < 2; ++kg)
            #pragma unroll
            for (int r = 0; r < 16; ++r) {
                const float p = __expf(accS[kg][r]);
                pv[kg][r] = p;
                l_loc += p;
            }

        // ---- O^T += Vh^T P^T (no exchange: permuted V^T; hi-only) ----
        #pragma unroll
        for (int kp = 0; kp < 4; ++kp) {
            const int kg = kp >> 1;
            const int t8 = (kp & 1) * 8;
            fragu ph;
            #pragma unroll
            for (int j2 = 0; j2 < 4; ++j2)
                ph.u[j2] = f2bf(pv[kg][t8 + 2 * j2]) |
                           (f2bf(pv[kg][t8 + 2 * j2 + 1]) << 16);
            #pragma unroll
            for (int dt = 0; dt < 2; ++dt) {
                const bfrag vh = *(const bfrag*)&sVh[koff[dt][kp]];
                accO[dt] = __builtin_amdgcn_mfma_f32_32x32x16_bf16(vh, ph.f, accO[dt], 0, 0, 0);
            }
        }
    }

    // ---- accumulate partials (exactly 2 adds/element across kh blocks) ----
    const float lpart = l_loc + __shfl_xor(l_loc, 32);
    const int b = bh >> 4;
    const int h = bh & 15;
    const int sg = qt * 128 + w * 32 + l31;
    if (g == 0) atomicAdd(&lsum[bh * 2048 + sg], lpart);
    const size_t ob = ((size_t)sg * BATCH + b) * DMODEL + h * 64;
    #pragma unroll
    for (int dt = 0; dt < 2; ++dt)
        #pragma unroll
        for (int rq = 0; rq < 4; ++rq) {
            const int d0 = 8 * rq + 4 * g + 32 * dt;
            #pragma unroll
            for (int i2 = 0; i2 < 4; ++i2)
                atomicAdd(&AOf[ob + d0 + i2], accO[dt][rq * 4 + i2]);
        }
}

// combine: normalize by lsum, emit blocked hi/lo A for the final GEMM
__global__ __launch_bounds__(256) void combine_kernel(
    const float* __restrict__ AOf, const float* __restrict__ lsum,
    u16* __restrict__ AOb)
{
    const int i  = blockIdx.x * 256 + threadIdx.x;   // 0..524287, 8 elems each
    const int rm = i >> 7;
    const int k0 = (i & 127) * 8;
    float xs[8];
    *(float4*)&xs[0] = ((const float4*)AOf)[rm * 256 + (k0 >> 2)];
    *(float4*)&xs[4] = ((const float4*)AOf)[rm * 256 + (k0 >> 2) + 1];
    const int h = k0 >> 6, s = rm >> 1, bb = rm & 1;
    const float linv = 1.0f / lsum[(bb * NHEADS + h) * 2048 + s];
    __align__(16) u16 hb[8];
    __align__(16) u16 lb[8];
    #pragma unroll
    for (int j = 0; j < 8; ++j) {
        const float v = xs[j] * linv;
        const u32 hh = f2bf(v);
        hb[j] = (u16)hh;
        lb[j] = (u16)f2bf(v - bf2f(hh));
    }
    u16* o = AOb + (size_t)rm * 2048 + (k0 >> 5) * 64 + (k0 & 31);
    *(uint4*)o        = *(const uint4*)hb;
    *(uint4*)(o + 32) = *(const uint4*)lb;
}

// ---------------------------------------------------------------------------
extern "C" void kernel_launch(void* const* d_in, const int* in_sizes, int n_in,
                              void* d_out, int out_size, void* d_ws, size_t ws_size,
                              hipStream_t stream)
{
    float* query = (float*)d_in[0];       // packed in place by prep
    float* key   = (float*)d_in[1];
    float* value = (float*)d_in[2];
    const float* Wq    = (const float*)d_in[3];
    const float* bq    = (const float*)d_in[4];
    const float* Wk    = (const float*)d_in[5];
    const float* bk    = (const float*)d_in[6];
    const float* Wv    = (const float*)d_in[7];
    const float* bv    = (const float*)d_in[8];
    const float* Wo    = (const float*)d_in[9];
    const float* bo    = (const float*)d_in[10];
    float* out = (float*)d_out;

    // 64 MB workspace, time-multiplexed (MB offsets):
    //  Wqb [0,4) Wkb [4,8) Wvb [8,12) tab [12,12.5)  -- dead after qkv
    //  Qh [16,24) Ql [24,32) Kh [32,40) Kl [40,48) VTh [48,56)
    //  AOf fp32 [0,16)  (atomic partials; zeroed after qkv)
    //  lsum [56,56.25)
    //  AOb blocked [32,48)  (Kh/Kl dead after attn)
    //  Wob [16,20)          (Q dead after attn)
    char* wsb = (char*)d_ws;
    const size_t MB = 1024 * 1024;
    u16* Wqb = (u16*)(wsb + 0 * MB);
    u16* Wkb = (u16*)(wsb + 4 * MB);
    u16* Wvb = (u16*)(wsb + 8 * MB);
    float2* tab = (float2*)(wsb + 12 * MB);
    u16* Qh  = (u16*)(wsb + 16 * MB); u16* Ql  = (u16*)(wsb + 24 * MB);
    u16* Kh  = (u16*)(wsb + 32 * MB); u16* Kl  = (u16*)(wsb + 40 * MB);
    u16* VTh = (u16*)(wsb + 48 * MB);
    float* AOf  = (float*)(wsb + 0 * MB);
    float* lsum = (float*)(wsb + 56 * MB);
    u16* AOb = (u16*)(wsb + 32 * MB);
    u16* Wob = (u16*)(wsb + 16 * MB);

    // pack weights (ws) + inputs (in place, blocked) + RoPE table
    prep_kernel<<<dim3(512, 7), 256, 0, stream>>>(
        Wq, Wk, Wv, query, key, value, Wqb, Wkb, Wvb, tab);
    // merged Q/K/V projections (+RoPE for Q/K; Q pre-scaled; V writes V^T hi)
    qkv_gemm_kernel<<<dim3(16, 32, 3), 256, 0, stream>>>(
        (const u16*)query, (const u16*)key, (const u16*)value,
        Wqb, Wkb, Wvb, bq, bk, bv, tab, Qh, Ql, Kh, Kl, VTh);
    // zero atomic targets, then split-K attention
    zero_kernel<<<dim3(4096, 2), 256, 0, stream>>>(AOf, lsum);
    attn_mfma_kernel<<<dim3(16, 32, 2), 256, 0, stream>>>(
        Qh, Ql, Kh, Kl, VTh, AOf, lsum);
    // normalize + blocked-pack attn output
    combine_kernel<<<2048, 256, 0, stream>>>(AOf, lsum, AOb);
    // output projection
    pack_kernel<<<512, 256, 0, stream>>>(Wo, Wob);
    out_gemm_kernel<<<dim3(32, 32), 256, 0, stream>>>(AOb, Wob, bo, out);
}

// Round 11
// 319.791 us; speedup vs baseline: 1.5489x; 1.5489x over previous
//
#include <hip/hip_runtime.h>

// Problem constants
#define DMODEL 1024
#define NHEADS 16
#define HDIM   64
#define SEQ    2048
#define BATCH  2
#define MROWS  (SEQ*BATCH)   // 4096

typedef unsigned int u32;
typedef unsigned short u16;
typedef __attribute__((ext_vector_type(8))) short bfrag;    // 8 bf16 (A/B frag)
typedef __attribute__((ext_vector_type(4))) float f32x4;    // 16x16 C/D frag
typedef __attribute__((ext_vector_type(16))) float f32x16;  // 32x32 C/D frag
typedef union { u32 u[4]; bfrag f; } fragu;

// bf16 split helpers (RTN-even hi). x ~= hi + lo
__device__ __forceinline__ u32 f2bf(float x) {
    unsigned u = __float_as_uint(x);
    return (u + 0x7fffu + ((u >> 16) & 1u)) >> 16;
}
__device__ __forceinline__ float bf2f(u32 h) {
    return __uint_as_float(h << 16);
}

// async global->LDS, 16B/lane; LDS dest = wave-uniform base (+lane*16 by HW)
__device__ __forceinline__ void gld16(const void* g, void* l) {
    __builtin_amdgcn_global_load_lds(
        (const __attribute__((address_space(1))) unsigned int*)g,
        (__attribute__((address_space(3))) unsigned int*)l, 16, 0, 0);
}

// ---------------------------------------------------------------------------
// BLOCKED hi/lo format: each row of 1024 elems = 32 groups of 32; group t
// occupies 64 u16: [32 hi][32 lo]. Frag reads are direct ds_read_b128
// (hi chunk = lquad, lo chunk = 4+lquad within the 128B group) — no unpack.
// ---------------------------------------------------------------------------

// Prep:
//  y=0..2 : Wq/Wk/Wv -> blocked hi/lo into ws              (512 blocks, 8/thr)
//  y=3    : f64-accurate RoPE table                         (256 blocks)
//  y=4..6 : query/key/value packed IN PLACE to blocked      (512 blocks, 32/thr
//           = one full 128B group per thread -> race-free in place)
__global__ __launch_bounds__(256) void prep_kernel(
    const float* __restrict__ Wq, const float* __restrict__ Wk,
    const float* __restrict__ Wv,
    float* __restrict__ query, float* __restrict__ key, float* __restrict__ value,
    u16* __restrict__ wqb, u16* __restrict__ wkb, u16* __restrict__ wvb,
    float2* __restrict__ tab)
{
    const int y = blockIdx.y;
    if (y == 3) {
        if (blockIdx.x >= 256) return;
        const int e = blockIdx.x * 256 + threadIdx.x;   // 65536 = 2048 s x 32 i
        const int s = e >> 5, i = e & 31;
        const double th = exp(-(double)i * (9.210340371976184 / 32.0)); // ln(1e4)/32
        double sn, cs;
        sincos((double)s * th, &sn, &cs);
        tab[e] = make_float2((float)sn, (float)cs);
        return;
    }
    if (y < 3) {
        const float* src = (y == 0) ? Wq : (y == 1) ? Wk : Wv;
        u16* dst = (y == 0) ? wqb : (y == 1) ? wkb : wvb;
        const int i = blockIdx.x * 256 + threadIdx.x;   // 8 elems/thread
        const int e0  = i * 8;
        const int row = e0 >> 10, k = e0 & 1023, t = k >> 5, j0 = k & 31;
        float xs[8];
        *(float4*)&xs[0] = ((const float4*)src)[i * 2];
        *(float4*)&xs[4] = ((const float4*)src)[i * 2 + 1];
        __align__(16) u16 hb[8];
        __align__(16) u16 lb[8];
        #pragma unroll
        for (int j = 0; j < 8; ++j) {
            const u32 h = f2bf(xs[j]);
            hb[j] = (u16)h;
            lb[j] = (u16)f2bf(xs[j] - bf2f(h));
        }
        u16* o = dst + (size_t)row * 2048 + t * 64 + j0;
        *(uint4*)o        = *(const uint4*)hb;
        *(uint4*)(o + 32) = *(const uint4*)lb;
        return;
    }
    // in-place input pack: one 128B group (32 elems) per thread
    float* io = (y == 4) ? query : (y == 5) ? key : value;
    const int gi = blockIdx.x * 256 + threadIdx.x;      // 0..131071
    uint4* io4 = (uint4*)io + (size_t)gi * 8;
    uint4 raw[8];
    #pragma unroll
    for (int j = 0; j < 8; ++j) raw[j] = io4[j];
    __align__(16) u16 hb[32];
    __align__(16) u16 lb[32];
    #pragma unroll
    for (int j = 0; j < 32; ++j) {
        const float x = __uint_as_float(((const u32*)raw)[j]);
        const u32 h = f2bf(x);
        hb[j] = (u16)h;
        lb[j] = (u16)f2bf(x - bf2f(h));
    }
    #pragma unroll
    for (int j = 0; j < 4; ++j) io4[j]     = ((const uint4*)hb)[j];
    #pragma unroll
    for (int j = 0; j < 4; ++j) io4[4 + j] = ((const uint4*)lb)[j];
}

// pack Wo -> blocked (runs after attn frees its ws slot)
__global__ __launch_bounds__(256) void pack_kernel(
    const float* __restrict__ src, u16* __restrict__ dst)
{
    const int i = blockIdx.x * 256 + threadIdx.x;
    const int e0  = i * 8;
    const int row = e0 >> 10, k = e0 & 1023, t = k >> 5, j0 = k & 31;
    float xs[8];
    *(float4*)&xs[0] = ((const float4*)src)[i * 2];
    *(float4*)&xs[4] = ((const float4*)src)[i * 2 + 1];
    __align__(16) u16 hb[8];
    __align__(16) u16 lb[8];
    #pragma unroll
    for (int j = 0; j < 8; ++j) {
        const u32 h = f2bf(xs[j]);
        hb[j] = (u16)h;
        lb[j] = (u16)f2bf(xs[j] - bf2f(h));
    }
    u16* o = dst + (size_t)row * 2048 + t * 64 + j0;
    *(uint4*)o        = *(const uint4*)hb;
    *(uint4*)(o + 32) = *(const uint4*)lb;
}

// ---------------------------------------------------------------------------
// Pipelined split-bf16 MFMA GEMM body, BLOCKED hi/lo operands (no unpack).
// BM=128, BN=NI*16; K in 32-wide half-steps, single barrier per step:
//   barrier -> issue next half's global_load_lds -> compute current half.
// LDS: sA 2x128x64 u16 = 32KB, sB 2x(NI*16)x64 u16 (16KB @ NI=4, 8KB @ NI=2).
// mode 0 (NI=4): RoPE(+scale)+split -> [b][h][s][d] bf16 hi/lo (Q/K)
// mode 1 (NI=4): bf16-hi, transposed + key-quartet-permuted -> V^T
// mode 2: fp32 row-major Mx1024
// ---------------------------------------------------------------------------
template <int NI>
__device__ __forceinline__ void gemm_body(
    int id, int mode,
    const u16* __restrict__ Ab, const u16* __restrict__ Wb,
    const float* __restrict__ bias, const float2* __restrict__ tab,
    float rope_scale,
    u16* __restrict__ Oh, u16* __restrict__ Ol, float* __restrict__ Of,
    u16* smem16)
{
    u16* sA = smem16;               // 2 halves x 128 rows x 64 u16
    u16* sB = smem16 + 16384;       // 2 halves x (NI*16) rows x 64 u16

    const int tid   = threadIdx.x;
    const int w     = tid >> 6;
    const int lane  = tid & 63;
    const int lrow  = lane & 15;
    const int lquad = lane >> 4;

    // XCD-aware remap (id%8 ~ XCD; per XCD 4 m-tiles x all n-tiles)
    const int NBLK = 1024 / (NI * 16);
    const int xcd  = id & 7;
    const int jj   = id >> 3;
    const int nblk = jj & (NBLK - 1);
    const int mblk = (xcd << 2) | (jj / NBLK);
    const int n0   = nblk * NI * 16;
    const int m0   = mblk * 128;

    // staging coords: 8-row slabs, 8 chunks of 16B per 128B row-group
    const int srow8 = lane >> 3;
    const int sch   = (lane & 7) ^ srow8;

    // frag offsets (u16 units): hi chunk = lquad, lo chunk = 4+lquad
    int aoffh[2], aoffl[2], boffh[NI], boffl[NI];
    #pragma unroll
    for (int mi = 0; mi < 2; ++mi) {
        const int ra = w * 32 + mi * 16 + lrow;
        aoffh[mi] = ra * 64 + ((lquad ^ (ra & 7)) << 3);
        aoffl[mi] = ra * 64 + (((lquad + 4) ^ (ra & 7)) << 3);
    }
    #pragma unroll
    for (int ni = 0; ni < NI; ++ni) {
        const int rb = ni * 16 + lrow;
        boffh[ni] = rb * 64 + ((lquad ^ (rb & 7)) << 3);
        boffl[ni] = rb * 64 + (((lquad + 4) ^ (rb & 7)) << 3);
    }

    f32x4 acc[2][NI] = {};

    auto stage = [&](int t) {
        const int h = t & 1;
        #pragma unroll
        for (int i = 0; i < 4; ++i) {          // A: 16 gld16 total
            const int slab = w * 4 + i;
            const int row  = slab * 8 + srow8;
            gld16(Ab + (size_t)(m0 + row) * 2048 + t * 64 + sch * 8,
                  sA + h * 8192 + slab * 512);
        }
        #pragma unroll
        for (int i = 0; i < NI / 2; ++i) {     // B: 2*NI gld16 total
            const int slab = w * (NI / 2) + i;
            const int row  = slab * 8 + srow8;
            gld16(Wb + (size_t)(n0 + row) * 2048 + t * 64 + sch * 8,
                  sB + h * (NI * 1024) + slab * 512);
        }
    };

    stage(0);
    for (int t = 0; t < 32; ++t) {
        __syncthreads();                       // half t ready (vmcnt drained)
        if (t < 31) stage(t + 1);
        const int h = t & 1;
        const u16* sAh_ = sA + h * 8192;
        const u16* sBh_ = sB + h * (NI * 1024);

        bfrag ah[2], al[2], bh[NI], bl[NI];
        #pragma unroll
        for (int mi = 0; mi < 2; ++mi) {
            ah[mi] = *(const bfrag*)&sAh_[aoffh[mi]];
            al[mi] = *(const bfrag*)&sAh_[aoffl[mi]];
        }
        #pragma unroll
        for (int ni = 0; ni < NI; ++ni) {
            bh[ni] = *(const bfrag*)&sBh_[boffh[ni]];
            bl[ni] = *(const bfrag*)&sBh_[boffl[ni]];
        }

        #pragma unroll
        for (int mi = 0; mi < 2; ++mi)
            #pragma unroll
            for (int ni = 0; ni < NI; ++ni) {
                acc[mi][ni] = __builtin_amdgcn_mfma_f32_16x16x32_bf16(ah[mi], bh[ni], acc[mi][ni], 0, 0, 0);
                acc[mi][ni] = __builtin_amdgcn_mfma_f32_16x16x32_bf16(ah[mi], bl[ni], acc[mi][ni], 0, 0, 0);
                acc[mi][ni] = __builtin_amdgcn_mfma_f32_16x16x32_bf16(al[mi], bh[ni], acc[mi][ni], 0, 0, 0);
            }
    }

    float bn[NI];
    #pragma unroll
    for (int ni = 0; ni < NI; ++ni) bn[ni] = bias[n0 + ni * 16 + lrow];

    if constexpr (NI == 4) {
        if (mode == 0) {
            const int hblk = nblk;
            #pragma unroll
            for (int mi = 0; mi < 2; ++mi)
                #pragma unroll
                for (int r = 0; r < 4; ++r) {
                    const int mrow = w * 32 + mi * 16 + lquad * 4 + r;
                    const int m  = m0 + mrow;
                    const int bb = m & 1;
                    const int sg = m >> 1;
                    const size_t ob = (((size_t)(bb * NHEADS + hblk) * SEQ) + sg) * HDIM;
                    #pragma unroll
                    for (int ni = 0; ni < 2; ++ni) {
                        const int i = ni * 16 + lrow;
                        const float2 sc = tab[(size_t)sg * 32 + i];
                        const float x1 = acc[mi][ni][r]     + bn[ni];
                        const float x2 = acc[mi][ni + 2][r] + bn[ni + 2];
                        // reference quirk: o2 = x1*sin - x2*cos
                        const float o1 = (x1 * sc.y - x2 * sc.x) * rope_scale;
                        const float o2 = (x1 * sc.x - x2 * sc.y) * rope_scale;
                        const u32 h1 = f2bf(o1);
                        const u32 h2 = f2bf(o2);
                        Oh[ob + i]      = (u16)h1;  Ol[ob + i]      = (u16)f2bf(o1 - bf2f(h1));
                        Oh[ob + i + 32] = (u16)h2;  Ol[ob + i + 32] = (u16)f2bf(o2 - bf2f(h2));
                    }
                }
            return;
        }
        if (mode == 1) {
            // bf16-hi V^T, transposed via LDS (stride 65), key-quartet permuted
            __syncthreads();
            u32* vb = (u32*)smem16;    // 8320 u32 <= 48KB
            #pragma unroll
            for (int mi = 0; mi < 2; ++mi)
                #pragma unroll
                for (int r = 0; r < 4; ++r) {
                    const int mrow = w * 32 + mi * 16 + lquad * 4 + r;
                    const int bb = mrow & 1;
                    const int sl = mrow >> 1;
                    #pragma unroll
                    for (int ni = 0; ni < 4; ++ni) {
                        const int d = ni * 16 + lrow;
                        vb[bb * 4160 + d * 65 + sl] = f2bf(acc[mi][ni][r] + bn[ni]);
                    }
                }
            __syncthreads();
            const int hblk = nblk;
            #pragma unroll
            for (int rep = 0; rep < 4; ++rep) {
                const int c  = rep * 256 + tid;      // 1024 chunks
                const int bb = c >> 9;
                const int d  = (c >> 3) & 63;
                const int s8 = c & 7;
                __align__(8) u16 hb[8];
                #pragma unroll
                for (int j = 0; j < 8; ++j)
                    hb[j] = (u16)vb[bb * 4160 + d * 65 + s8 * 8 + j];
                const size_t orow = ((size_t)(bb * NHEADS + hblk) * HDIM + d) * SEQ + (m0 >> 1);
                const int blk16 = (s8 >> 1) * 16;
                const int off   = (s8 & 1) * 4;
                *(uint2*)&Oh[orow + blk16 + off]     = *(const uint2*)&hb[0];
                *(uint2*)&Oh[orow + blk16 + 8 + off] = *(const uint2*)&hb[4];
            }
            return;
        }
    }
    // mode 2: fp32 row-major
    #pragma unroll
    for (int mi = 0; mi < 2; ++mi)
        #pragma unroll
        for (int r = 0; r < 4; ++r) {
            const int m = m0 + w * 32 + mi * 16 + lquad * 4 + r;
            #pragma unroll
            for (int ni = 0; ni < NI; ++ni)
                Of[(size_t)m * 1024 + n0 + ni * 16 + lrow] = acc[mi][ni][r] + bn[ni];
        }
}

// Merged Q/K/V projection: blockIdx.z selects projection (0=Q,1=K,2=V).
__global__ __launch_bounds__(256) void qkv_gemm_kernel(
    const u16* __restrict__ query, const u16* __restrict__ key,
    const u16* __restrict__ value,
    const u16* __restrict__ Wqb, const u16* __restrict__ Wkb,
    const u16* __restrict__ Wvb,
    const float* __restrict__ bq, const float* __restrict__ bk,
    const float* __restrict__ bv, const float2* __restrict__ tab,
    u16* __restrict__ Qh, u16* __restrict__ Ql,
    u16* __restrict__ Kh, u16* __restrict__ Kl,
    u16* __restrict__ VTh)
{
    __shared__ u16 smem16[24576];                 // 48 KB
    const int z  = blockIdx.z;
    const int id = blockIdx.x + 16 * blockIdx.y;
    const u16* A    = (z == 0) ? query : (z == 1) ? key : value;
    const u16* Wb   = (z == 0) ? Wqb : (z == 1) ? Wkb : Wvb;
    const float* bb = (z == 0) ? bq : (z == 1) ? bk : bv;
    u16* Oh = (z == 0) ? Qh : (z == 1) ? Kh : VTh;
    u16* Ol = (z == 0) ? Ql : (z == 1) ? Kl : nullptr;
    const int mode = (z == 2) ? 1 : 0;
    const float scale = (z == 0) ? 0.125f : 1.0f;
    gemm_body<4>(id, mode, A, Wb, bb, tab, scale, Oh, Ol, nullptr, smem16);
}

// Final projection: A = attn output (blocked), BN=32, grid 1024 (4 blk/CU).
__global__ __launch_bounds__(256) void out_gemm_kernel(
    const u16* __restrict__ Ab, const u16* __restrict__ Wb,
    const float* __restrict__ bias, float* __restrict__ Of)
{
    __shared__ u16 smem16[20480];                 // 40 KB
    const int id = blockIdx.x + 32 * blockIdx.y;
    gemm_body<2>(id, 2, Ab, Wb, bias, nullptr, 1.0f, nullptr, nullptr, Of, smem16);
}

// ---------------------------------------------------------------------------
// MFMA flash attention (R9's proven structure): 32x32x16, no-max softmax,
// S^T/O^T form, DOUBLE-BUFFERED K/V tiles (single barrier/iter), register-P,
// no cross-lane exchange (key-quartet-permuted V^T), P/V bf16-hi only.
// Block = 256 threads (4 waves) = 128 q-rows; grid 512.
// LDS = 48 KB (dbuf Kh/Kl/Vh). Output: BLOCKED hi/lo (S,B,DMODEL) rows.
// ---------------------------------------------------------------------------
__global__ __launch_bounds__(256) void attn_mfma_kernel(
    const u16* __restrict__ Qh, const u16* __restrict__ Ql,
    const u16* __restrict__ Kh, const u16* __restrict__ Kl,
    const u16* __restrict__ Vh,
    u16* __restrict__ AOb)
{
    __shared__ u16 sKh[8192], sKl[8192];   // [buf][key][dh] swizzled
    __shared__ u16 sVh[8192];              // [buf][dh][key'] swizzled (permuted)

    const int tid  = threadIdx.x;
    const int w    = tid >> 6;             // 0..3
    const int lane = tid & 63;
    const int l31  = lane & 31;
    const int g    = lane >> 5;

    // XCD-aware remap: 4 bh per XCD so K/V tiles are L2-local
    const int id = blockIdx.x + 16 * blockIdx.y;   // 0..511
    const int jj = id >> 3;                        // 0..63
    const int bh = ((id & 7) << 2) | (jj >> 4);
    const int qt = jj & 15;

    // Q B-frags (registers): col=q=l31, k = ks*16 + g*8 + j
    const size_t qg = ((size_t)bh * SEQ + qt * 128 + w * 32 + l31) * HDIM + g * 8;
    bfrag qfh[4], qfl[4];
    #pragma unroll
    for (int ks = 0; ks < 4; ++ks) {
        qfh[ks] = *(const bfrag*)&Qh[qg + ks * 16];
        qfl[ks] = *(const bfrag*)&Ql[qg + ks * 16];
    }

    // staging: wave 0->sKh, 1->sKl, 2->sVh, 3 idle; 8 gld16 x 1KB each
    const int srow   = lane >> 3;
    const int schunk = (lane & 7) ^ srow;
    const u16* gsrc = nullptr; u16* lbase = nullptr; size_t istep = 0, ktstep = 0;
    if (w == 0) {
        gsrc = Kh + ((size_t)bh * SEQ + srow) * HDIM + schunk * 8;
        istep = 8 * 64; ktstep = 64 * 64; lbase = sKh;
    } else if (w == 1) {
        gsrc = Kl + ((size_t)bh * SEQ + srow) * HDIM + schunk * 8;
        istep = 8 * 64; ktstep = 64 * 64; lbase = sKl;
    } else if (w == 2) {
        gsrc = Vh + ((size_t)bh * HDIM + srow) * SEQ + schunk * 8;
        istep = 8 * SEQ; ktstep = 64; lbase = sVh;
    }

    // frag offsets (u16 units): row-block a (32 rows), 16B chunk c of 8
    int koff[2][4];
    #pragma unroll
    for (int a = 0; a < 2; ++a) {
        const int row = a * 32 + l31;
        #pragma unroll
        for (int c = 0; c < 4; ++c)
            koff[a][c] = row * 64 + (((c * 2 + g) ^ (row & 7)) << 3);
    }

    f32x16 accO[2] = {};
    float l_loc = 0.0f;

    auto stage = [&](int kt) {
        if (w < 3) {
            const u16* gp = gsrc + (size_t)kt * ktstep;
            u16* dst = lbase + (kt & 1) * 4096;
            #pragma unroll
            for (int i = 0; i < 8; ++i)
                gld16(gp + (size_t)i * istep, dst + i * 512);
        }
    };

    stage(0);
    for (int kt = 0; kt < SEQ / 64; ++kt) {
        __syncthreads();                     // tile kt ready (vmcnt drained)
        if (kt < SEQ / 64 - 1) stage(kt + 1);
        const int po = (kt & 1) * 4096;

        // ---- S^T = K Q^T (Q pre-scaled) : lane=q, regs=keys ----
        f32x16 accS[2] = {};
        #pragma unroll
        for (int kg = 0; kg < 2; ++kg)
            #pragma unroll
            for (int ks = 0; ks < 4; ++ks) {
                const bfrag kh_ = *(const bfrag*)&sKh[po + koff[kg][ks]];
                const bfrag kl_ = *(const bfrag*)&sKl[po + koff[kg][ks]];
                accS[kg] = __builtin_amdgcn_mfma_f32_32x32x16_bf16(kh_, qfh[ks], accS[kg], 0, 0, 0);
                accS[kg] = __builtin_amdgcn_mfma_f32_32x32x16_bf16(kh_, qfl[ks], accS[kg], 0, 0, 0);
                accS[kg] = __builtin_amdgcn_mfma_f32_32x32x16_bf16(kl_, qfh[ks], accS[kg], 0, 0, 0);
            }

        // ---- p = exp(s) in registers (lane=q, reg=key) ----
        float pv[2][16];
        #pragma unroll
        for (int kg = 0; kg < 2; ++kg)
            #pragma unroll
            for (int r = 0; r < 16; ++r) {
                const float p = __expf(accS[kg][r]);
                pv[kg][r] = p;
                l_loc += p;
            }

        // ---- O^T += Vh^T P^T (no exchange: permuted V^T; hi-only) ----
        #pragma unroll
        for (int kp = 0; kp < 4; ++kp) {
            const int kg = kp >> 1;
            const int t8 = (kp & 1) * 8;
            fragu ph;
            #pragma unroll
            for (int j2 = 0; j2 < 4; ++j2)
                ph.u[j2] = f2bf(pv[kg][t8 + 2 * j2]) |
                           (f2bf(pv[kg][t8 + 2 * j2 + 1]) << 16);
            #pragma unroll
            for (int dt = 0; dt < 2; ++dt) {
                const bfrag vh = *(const bfrag*)&sVh[po + koff[dt][kp]];
                accO[dt] = __builtin_amdgcn_mfma_f32_32x32x16_bf16(vh, ph.f, accO[dt], 0, 0, 0);
            }
        }
    }

    // ---- l: combine complementary g-halves; write BLOCKED hi/lo output ----
    const float inv = 1.0f / (l_loc + __shfl_xor(l_loc, 32));

    const int b = bh >> 4;
    const int h = bh & 15;
    const int sg = qt * 128 + w * 32 + l31;
    const int rm = sg * BATCH + b;                 // output row (0..4095)
    #pragma unroll
    for (int dt = 0; dt < 2; ++dt)
        #pragma unroll
        for (int rq = 0; rq < 4; ++rq) {
            const int j0 = 8 * rq + 4 * g;         // pos within 32-group
            const int t  = h * 2 + dt;             // group index
            __align__(8) u16 hb[4];
            __align__(8) u16 lb[4];
            #pragma unroll
            for (int i2 = 0; i2 < 4; ++i2) {
                const float v = accO[dt][rq * 4 + i2] * inv;
                const u32 hh = f2bf(v);
                hb[i2] = (u16)hh;
                lb[i2] = (u16)f2bf(v - bf2f(hh));
            }
            u16* o = AOb + (size_t)rm * 2048 + t * 64 + j0;
            *(uint2*)o        = *(const uint2*)hb;
            *(uint2*)(o + 32) = *(const uint2*)lb;
        }
}

// ---------------------------------------------------------------------------
extern "C" void kernel_launch(void* const* d_in, const int* in_sizes, int n_in,
                              void* d_out, int out_size, void* d_ws, size_t ws_size,
                              hipStream_t stream)
{
    float* query = (float*)d_in[0];       // packed in place by prep
    float* key   = (float*)d_in[1];
    float* value = (float*)d_in[2];
    const float* Wq    = (const float*)d_in[3];
    const float* bq    = (const float*)d_in[4];
    const float* Wk    = (const float*)d_in[5];
    const float* bk    = (const float*)d_in[6];
    const float* Wv    = (const float*)d_in[7];
    const float* bv    = (const float*)d_in[8];
    const float* Wo    = (const float*)d_in[9];
    const float* bo    = (const float*)d_in[10];
    float* out = (float*)d_out;

    // 64 MB workspace, time-multiplexed (MB offsets):
    //  Wqb [0,4) Wkb [4,8) Wvb [8,12) tab [12,12.5)  -- dead after qkv
    //  Qh [16,24) Ql [24,32) Kh [32,40) Kl [40,48) VTh [48,56)
    //  AOb blocked [0,16)   (W-packs + tab dead after qkv)
    //  Wob [16,20)          (Q dead after attn)
    char* wsb = (char*)d_ws;
    const size_t MB = 1024 * 1024;
    u16* Wqb = (u16*)(wsb + 0 * MB);
    u16* Wkb = (u16*)(wsb + 4 * MB);
    u16* Wvb = (u16*)(wsb + 8 * MB);
    float2* tab = (float2*)(wsb + 12 * MB);
    u16* Qh  = (u16*)(wsb + 16 * MB); u16* Ql  = (u16*)(wsb + 24 * MB);
    u16* Kh  = (u16*)(wsb + 32 * MB); u16* Kl  = (u16*)(wsb + 40 * MB);
    u16* VTh = (u16*)(wsb + 48 * MB);
    u16* AOb = (u16*)(wsb + 0 * MB);
    u16* Wob = (u16*)(wsb + 16 * MB);

    // pack weights (ws) + inputs (in place, blocked) + RoPE table
    prep_kernel<<<dim3(512, 7), 256, 0, stream>>>(
        Wq, Wk, Wv, query, key, value, Wqb, Wkb, Wvb, tab);
    // merged Q/K/V projections (+RoPE for Q/K; Q pre-scaled; V writes V^T hi)
    qkv_gemm_kernel<<<dim3(16, 32, 3), 256, 0, stream>>>(
        (const u16*)query, (const u16*)key, (const u16*)value,
        Wqb, Wkb, Wvb, bq, bk, bv, tab, Qh, Ql, Kh, Kl, VTh);
    // attention -> blocked hi/lo (S,B,D)
    attn_mfma_kernel<<<dim3(16, 32), 256, 0, stream>>>(
        Qh, Ql, Kh, Kl, VTh, AOb);
    // output projection
    pack_kernel<<<512, 256, 0, stream>>>(Wo, Wob);
    out_gemm_kernel<<<dim3(32, 32), 256, 0, stream>>>(AOb, Wob, bo, out);
}

// Round 12
// 309.304 us; speedup vs baseline: 1.6014x; 1.0339x over previous
//
#include <hip/hip_runtime.h>
#include <hip/hip_bf16.h>

// Problem constants
#define DMODEL 1024
#define NHEADS 16
#define HDIM   64
#define SEQ    2048
#define BATCH  2
#define MROWS  (SEQ*BATCH)   // 4096

typedef unsigned int u32;
typedef unsigned short u16;
typedef __attribute__((ext_vector_type(8))) short bfrag;    // 8 bf16 (A/B frag)
typedef __attribute__((ext_vector_type(4))) float f32x4;    // 16x16 C/D frag
typedef __attribute__((ext_vector_type(16))) float f32x16;  // 32x32 C/D frag
typedef union { u32 u[4]; bfrag f; } fragu;

#define LOG2E 1.44269504088896341f

// bf16 split helpers (RTN-even hi). x ~= hi + lo
__device__ __forceinline__ u32 f2bf(float x) {
    unsigned u = __float_as_uint(x);
    return (u + 0x7fffu + ((u >> 16) & 1u)) >> 16;
}
__device__ __forceinline__ float bf2f(u32 h) {
    return __uint_as_float(h << 16);
}
// packed 2xf32 -> 2xbf16 (v_cvt_pk_bf16_f32 on gfx950), a=low, b=high
__device__ __forceinline__ u32 pk2bf(float a, float b) {
    __hip_bfloat162 t = __float22bfloat162_rn(make_float2(a, b));
    u32 r;
    __builtin_memcpy(&r, &t, 4);
    return r;
}
__device__ __forceinline__ float fexp2(float x) {
#if __has_builtin(__builtin_amdgcn_exp2f)
    return __builtin_amdgcn_exp2f(x);
#else
    return exp2f(x);
#endif
}

// async global->LDS, 16B/lane; LDS dest = wave-uniform base (+lane*16 by HW)
__device__ __forceinline__ void gld16(const void* g, void* l) {
    __builtin_amdgcn_global_load_lds(
        (const __attribute__((address_space(1))) unsigned int*)g,
        (__attribute__((address_space(3))) unsigned int*)l, 16, 0, 0);
}

// ---------------------------------------------------------------------------
// BLOCKED hi/lo format: each row of 1024 elems = 32 groups of 32; group t
// occupies 64 u16: [32 hi][32 lo]. Frag reads are direct ds_read_b128
// (hi chunk = lquad, lo chunk = 4+lquad within the 128B group) — no unpack.
// ---------------------------------------------------------------------------

// Prep:
//  y=0..2 : Wq/Wk/Wv -> blocked hi/lo into ws              (512 blocks, 8/thr)
//  y=3    : f64-accurate RoPE table                         (256 blocks)
//  y=4..6 : query/key/value packed IN PLACE to blocked      (512 blocks, 32/thr
//           = one full 128B group per thread -> race-free in place)
//  y=7    : Wo -> blocked into ws                           (512 blocks)
__global__ __launch_bounds__(256) void prep_kernel(
    const float* __restrict__ Wq, const float* __restrict__ Wk,
    const float* __restrict__ Wv, const float* __restrict__ Wo,
    float* __restrict__ query, float* __restrict__ key, float* __restrict__ value,
    u16* __restrict__ wqb, u16* __restrict__ wkb, u16* __restrict__ wvb,
    u16* __restrict__ wob, float2* __restrict__ tab)
{
    const int y = blockIdx.y;
    if (y == 3) {
        if (blockIdx.x >= 256) return;
        const int e = blockIdx.x * 256 + threadIdx.x;   // 65536 = 2048 s x 32 i
        const int s = e >> 5, i = e & 31;
        const double th = exp(-(double)i * (9.210340371976184 / 32.0)); // ln(1e4)/32
        double sn, cs;
        sincos((double)s * th, &sn, &cs);
        tab[e] = make_float2((float)sn, (float)cs);
        return;
    }
    if (y < 3 || y == 7) {
        const float* src = (y == 0) ? Wq : (y == 1) ? Wk : (y == 2) ? Wv : Wo;
        u16* dst = (y == 0) ? wqb : (y == 1) ? wkb : (y == 2) ? wvb : wob;
        const int i = blockIdx.x * 256 + threadIdx.x;   // 8 elems/thread
        const int e0  = i * 8;
        const int row = e0 >> 10, k = e0 & 1023, t = k >> 5, j0 = k & 31;
        float xs[8];
        *(float4*)&xs[0] = ((const float4*)src)[i * 2];
        *(float4*)&xs[4] = ((const float4*)src)[i * 2 + 1];
        __align__(16) u16 hb[8];
        __align__(16) u16 lb[8];
        #pragma unroll
        for (int j = 0; j < 8; ++j) {
            const u32 h = f2bf(xs[j]);
            hb[j] = (u16)h;
            lb[j] = (u16)f2bf(xs[j] - bf2f(h));
        }
        u16* o = dst + (size_t)row * 2048 + t * 64 + j0;
        *(uint4*)o        = *(const uint4*)hb;
        *(uint4*)(o + 32) = *(const uint4*)lb;
        return;
    }
    // in-place input pack: one 128B group (32 elems) per thread
    float* io = (y == 4) ? query : (y == 5) ? key : value;
    const int gi = blockIdx.x * 256 + threadIdx.x;      // 0..131071
    uint4* io4 = (uint4*)io + (size_t)gi * 8;
    uint4 raw[8];
    #pragma unroll
    for (int j = 0; j < 8; ++j) raw[j] = io4[j];
    __align__(16) u16 hb[32];
    __align__(16) u16 lb[32];
    #pragma unroll
    for (int j = 0; j < 32; ++j) {
        const float x = __uint_as_float(((const u32*)raw)[j]);
        const u32 h = f2bf(x);
        hb[j] = (u16)h;
        lb[j] = (u16)f2bf(x - bf2f(h));
    }
    #pragma unroll
    for (int j = 0; j < 4; ++j) io4[j]     = ((const uint4*)hb)[j];
    #pragma unroll
    for (int j = 0; j < 4; ++j) io4[4 + j] = ((const uint4*)lb)[j];
}

// ---------------------------------------------------------------------------
// Pipelined split-bf16 MFMA GEMM body, BLOCKED hi/lo operands (no unpack).
// BM=128, BN=NI*16; K in 32-wide half-steps, single barrier per step:
//   barrier -> issue next half's global_load_lds -> compute current half.
// LDS: sA 2x128x64 u16 = 32KB, sB 2x(NI*16)x64 u16 (16KB @ NI=4, 8KB @ NI=2).
// mode 0 (NI=4): RoPE(+scale)+split -> [b][h][s][d] bf16 hi/lo (Q/K)
// mode 1 (NI=4): bf16-hi, transposed + key-quartet-permuted -> V^T
// mode 2: fp32 row-major Mx1024
// ---------------------------------------------------------------------------
template <int NI>
__device__ __forceinline__ void gemm_body(
    int id, int mode,
    const u16* __restrict__ Ab, const u16* __restrict__ Wb,
    const float* __restrict__ bias, const float2* __restrict__ tab,
    float rope_scale,
    u16* __restrict__ Oh, u16* __restrict__ Ol, float* __restrict__ Of,
    u16* smem16)
{
    u16* sA = smem16;               // 2 halves x 128 rows x 64 u16
    u16* sB = smem16 + 16384;       // 2 halves x (NI*16) rows x 64 u16

    const int tid   = threadIdx.x;
    const int w     = tid >> 6;
    const int lane  = tid & 63;
    const int lrow  = lane & 15;
    const int lquad = lane >> 4;

    // XCD-aware remap (id%8 ~ XCD; per XCD 4 m-tiles x all n-tiles)
    const int NBLK = 1024 / (NI * 16);
    const int xcd  = id & 7;
    const int jj   = id >> 3;
    const int nblk = jj & (NBLK - 1);
    const int mblk = (xcd << 2) | (jj / NBLK);
    const int n0   = nblk * NI * 16;
    const int m0   = mblk * 128;

    // staging coords: 8-row slabs, 8 chunks of 16B per 128B row-group
    const int srow8 = lane >> 3;
    const int sch   = (lane & 7) ^ srow8;

    // frag offsets (u16 units): hi chunk = lquad, lo chunk = 4+lquad
    int aoffh[2], aoffl[2], boffh[NI], boffl[NI];
    #pragma unroll
    for (int mi = 0; mi < 2; ++mi) {
        const int ra = w * 32 + mi * 16 + lrow;
        aoffh[mi] = ra * 64 + ((lquad ^ (ra & 7)) << 3);
        aoffl[mi] = ra * 64 + (((lquad + 4) ^ (ra & 7)) << 3);
    }
    #pragma unroll
    for (int ni = 0; ni < NI; ++ni) {
        const int rb = ni * 16 + lrow;
        boffh[ni] = rb * 64 + ((lquad ^ (rb & 7)) << 3);
        boffl[ni] = rb * 64 + (((lquad + 4) ^ (rb & 7)) << 3);
    }

    f32x4 acc[2][NI] = {};

    auto stage = [&](int t) {
        const int h = t & 1;
        #pragma unroll
        for (int i = 0; i < 4; ++i) {          // A: 16 gld16 total
            const int slab = w * 4 + i;
            const int row  = slab * 8 + srow8;
            gld16(Ab + (size_t)(m0 + row) * 2048 + t * 64 + sch * 8,
                  sA + h * 8192 + slab * 512);
        }
        #pragma unroll
        for (int i = 0; i < NI / 2; ++i) {     // B: 2*NI gld16 total
            const int slab = w * (NI / 2) + i;
            const int row  = slab * 8 + srow8;
            gld16(Wb + (size_t)(n0 + row) * 2048 + t * 64 + sch * 8,
                  sB + h * (NI * 1024) + slab * 512);
        }
    };

    stage(0);
    for (int t = 0; t < 32; ++t) {
        __syncthreads();                       // half t ready (vmcnt drained)
        if (t < 31) stage(t + 1);
        const int h = t & 1;
        const u16* sAh_ = sA + h * 8192;
        const u16* sBh_ = sB + h * (NI * 1024);

        bfrag ah[2], al[2], bh[NI], bl[NI];
        #pragma unroll
        for (int mi = 0; mi < 2; ++mi) {
            ah[mi] = *(const bfrag*)&sAh_[aoffh[mi]];
            al[mi] = *(const bfrag*)&sAh_[aoffl[mi]];
        }
        #pragma unroll
        for (int ni = 0; ni < NI; ++ni) {
            bh[ni] = *(const bfrag*)&sBh_[boffh[ni]];
            bl[ni] = *(const bfrag*)&sBh_[boffl[ni]];
        }

        #pragma unroll
        for (int mi = 0; mi < 2; ++mi)
            #pragma unroll
            for (int ni = 0; ni < NI; ++ni) {
                acc[mi][ni] = __builtin_amdgcn_mfma_f32_16x16x32_bf16(ah[mi], bh[ni], acc[mi][ni], 0, 0, 0);
                acc[mi][ni] = __builtin_amdgcn_mfma_f32_16x16x32_bf16(ah[mi], bl[ni], acc[mi][ni], 0, 0, 0);
                acc[mi][ni] = __builtin_amdgcn_mfma_f32_16x16x32_bf16(al[mi], bh[ni], acc[mi][ni], 0, 0, 0);
            }
    }

    float bn[NI];
    #pragma unroll
    for (int ni = 0; ni < NI; ++ni) bn[ni] = bias[n0 + ni * 16 + lrow];

    if constexpr (NI == 4) {
        if (mode == 0) {
            const int hblk = nblk;
            #pragma unroll
            for (int mi = 0; mi < 2; ++mi)
                #pragma unroll
                for (int r = 0; r < 4; ++r) {
                    const int mrow = w * 32 + mi * 16 + lquad * 4 + r;
                    const int m  = m0 + mrow;
                    const int bb = m & 1;
                    const int sg = m >> 1;
                    const size_t ob = (((size_t)(bb * NHEADS + hblk) * SEQ) + sg) * HDIM;
                    #pragma unroll
                    for (int ni = 0; ni < 2; ++ni) {
                        const int i = ni * 16 + lrow;
                        const float2 sc = tab[(size_t)sg * 32 + i];
                        const float x1 = acc[mi][ni][r]     + bn[ni];
                        const float x2 = acc[mi][ni + 2][r] + bn[ni + 2];
                        // reference quirk: o2 = x1*sin - x2*cos
                        const float o1 = (x1 * sc.y - x2 * sc.x) * rope_scale;
                        const float o2 = (x1 * sc.x - x2 * sc.y) * rope_scale;
                        const u32 h1 = f2bf(o1);
                        const u32 h2 = f2bf(o2);
                        Oh[ob + i]      = (u16)h1;  Ol[ob + i]      = (u16)f2bf(o1 - bf2f(h1));
                        Oh[ob + i + 32] = (u16)h2;  Ol[ob + i + 32] = (u16)f2bf(o2 - bf2f(h2));
                    }
                }
            return;
        }
        if (mode == 1) {
            // bf16-hi V^T, transposed via LDS (stride 65), key-quartet permuted
            __syncthreads();
            u32* vb = (u32*)smem16;    // 8320 u32 <= 48KB
            #pragma unroll
            for (int mi = 0; mi < 2; ++mi)
                #pragma unroll
                for (int r = 0; r < 4; ++r) {
                    const int mrow = w * 32 + mi * 16 + lquad * 4 + r;
                    const int bb = mrow & 1;
                    const int sl = mrow >> 1;
                    #pragma unroll
                    for (int ni = 0; ni < 4; ++ni) {
                        const int d = ni * 16 + lrow;
                        vb[bb * 4160 + d * 65 + sl] = f2bf(acc[mi][ni][r] + bn[ni]);
                    }
                }
            __syncthreads();
            const int hblk = nblk;
            #pragma unroll
            for (int rep = 0; rep < 4; ++rep) {
                const int c  = rep * 256 + tid;      // 1024 chunks
                const int bb = c >> 9;
                const int d  = (c >> 3) & 63;
                const int s8 = c & 7;
                __align__(8) u16 hb[8];
                #pragma unroll
                for (int j = 0; j < 8; ++j)
                    hb[j] = (u16)vb[bb * 4160 + d * 65 + s8 * 8 + j];
                const size_t orow = ((size_t)(bb * NHEADS + hblk) * HDIM + d) * SEQ + (m0 >> 1);
                const int blk16 = (s8 >> 1) * 16;
                const int off   = (s8 & 1) * 4;
                *(uint2*)&Oh[orow + blk16 + off]     = *(const uint2*)&hb[0];
                *(uint2*)&Oh[orow + blk16 + 8 + off] = *(const uint2*)&hb[4];
            }
            return;
        }
    }
    // mode 2: fp32 row-major
    #pragma unroll
    for (int mi = 0; mi < 2; ++mi)
        #pragma unroll
        for (int r = 0; r < 4; ++r) {
            const int m = m0 + w * 32 + mi * 16 + lquad * 4 + r;
            #pragma unroll
            for (int ni = 0; ni < NI; ++ni)
                Of[(size_t)m * 1024 + n0 + ni * 16 + lrow] = acc[mi][ni][r] + bn[ni];
        }
}

// Merged Q/K/V projection: blockIdx.z selects projection (0=Q,1=K,2=V).
// Q is pre-scaled by (1/sqrt(64))*log2(e) so attention can use exp2 directly.
__global__ __launch_bounds__(256) void qkv_gemm_kernel(
    const u16* __restrict__ query, const u16* __restrict__ key,
    const u16* __restrict__ value,
    const u16* __restrict__ Wqb, const u16* __restrict__ Wkb,
    const u16* __restrict__ Wvb,
    const float* __restrict__ bq, const float* __restrict__ bk,
    const float* __restrict__ bv, const float2* __restrict__ tab,
    u16* __restrict__ Qh, u16* __restrict__ Ql,
    u16* __restrict__ Kh, u16* __restrict__ Kl,
    u16* __restrict__ VTh)
{
    __shared__ u16 smem16[24576];                 // 48 KB
    const int z  = blockIdx.z;
    const int id = blockIdx.x + 16 * blockIdx.y;
    const u16* A    = (z == 0) ? query : (z == 1) ? key : value;
    const u16* Wb   = (z == 0) ? Wqb : (z == 1) ? Wkb : Wvb;
    const float* bb = (z == 0) ? bq : (z == 1) ? bk : bv;
    u16* Oh = (z == 0) ? Qh : (z == 1) ? Kh : VTh;
    u16* Ol = (z == 0) ? Ql : (z == 1) ? Kl : nullptr;
    const int mode = (z == 2) ? 1 : 0;
    const float scale = (z == 0) ? 0.125f * LOG2E : 1.0f;
    gemm_body<4>(id, mode, A, Wb, bb, tab, scale, Oh, Ol, nullptr, smem16);
}

// Final projection: A = attn output (blocked), BN=32, grid 1024 (4 blk/CU).
__global__ __launch_bounds__(256) void out_gemm_kernel(
    const u16* __restrict__ Ab, const u16* __restrict__ Wb,
    const float* __restrict__ bias, float* __restrict__ Of)
{
    __shared__ u16 smem16[20480];                 // 40 KB
    const int id = blockIdx.x + 32 * blockIdx.y;
    gemm_body<2>(id, 2, Ab, Wb, bias, nullptr, 1.0f, nullptr, nullptr, Of, smem16);
}

// ---------------------------------------------------------------------------
// MFMA flash attention: 32x32x16, no-max softmax (exp2, Q pre-scaled by
// log2e/8), S^T/O^T form, DOUBLE-BUFFERED K/V tiles (single barrier/iter),
// register-P, no cross-lane exchange (key-quartet-permuted V^T), P/V hi-only,
// packed bf16 converts (v_cvt_pk_bf16_f32).
// Block = 256 threads (4 waves) = 128 q-rows; grid 512.
// LDS = 48 KB (dbuf Kh/Kl/Vh). Output: BLOCKED hi/lo (S,B,DMODEL) rows.
// ---------------------------------------------------------------------------
__global__ __launch_bounds__(256) void attn_mfma_kernel(
    const u16* __restrict__ Qh, const u16* __restrict__ Ql,
    const u16* __restrict__ Kh, const u16* __restrict__ Kl,
    const u16* __restrict__ Vh,
    u16* __restrict__ AOb)
{
    __shared__ u16 sKh[8192], sKl[8192];   // [buf][key][dh] swizzled
    __shared__ u16 sVh[8192];              // [buf][dh][key'] swizzled (permuted)

    const int tid  = threadIdx.x;
    const int w    = tid >> 6;             // 0..3
    const int lane = tid & 63;
    const int l31  = lane & 31;
    const int g    = lane >> 5;

    // XCD-aware remap: 4 bh per XCD so K/V tiles are L2-local
    const int id = blockIdx.x + 16 * blockIdx.y;   // 0..511
    const int jj = id >> 3;                        // 0..63
    const int bh = ((id & 7) << 2) | (jj >> 4);
    const int qt = jj & 15;

    // Q B-frags (registers): col=q=l31, k = ks*16 + g*8 + j
    const size_t qg = ((size_t)bh * SEQ + qt * 128 + w * 32 + l31) * HDIM + g * 8;
    bfrag qfh[4], qfl[4];
    #pragma unroll
    for (int ks = 0; ks < 4; ++ks) {
        qfh[ks] = *(const bfrag*)&Qh[qg + ks * 16];
        qfl[ks] = *(const bfrag*)&Ql[qg + ks * 16];
    }

    // staging: wave 0->sKh, 1->sKl, 2->sVh, 3 idle; 8 gld16 x 1KB each
    const int srow   = lane >> 3;
    const int schunk = (lane & 7) ^ srow;
    const u16* gsrc = nullptr; u16* lbase = nullptr; size_t istep = 0, ktstep = 0;
    if (w == 0) {
        gsrc = Kh + ((size_t)bh * SEQ + srow) * HDIM + schunk * 8;
        istep = 8 * 64; ktstep = 64 * 64; lbase = sKh;
    } else if (w == 1) {
        gsrc = Kl + ((size_t)bh * SEQ + srow) * HDIM + schunk * 8;
        istep = 8 * 64; ktstep = 64 * 64; lbase = sKl;
    } else if (w == 2) {
        gsrc = Vh + ((size_t)bh * HDIM + srow) * SEQ + schunk * 8;
        istep = 8 * SEQ; ktstep = 64; lbase = sVh;
    }

    // frag offsets (u16 units): row-block a (32 rows), 16B chunk c of 8
    int koff[2][4];
    #pragma unroll
    for (int a = 0; a < 2; ++a) {
        const int row = a * 32 + l31;
        #pragma unroll
        for (int c = 0; c < 4; ++c)
            koff[a][c] = row * 64 + (((c * 2 + g) ^ (row & 7)) << 3);
    }

    f32x16 accO[2] = {};
    float l_loc = 0.0f;

    auto stage = [&](int kt) {
        if (w < 3) {
            const u16* gp = gsrc + (size_t)kt * ktstep;
            u16* dst = lbase + (kt & 1) * 4096;
            #pragma unroll
            for (int i = 0; i < 8; ++i)
                gld16(gp + (size_t)i * istep, dst + i * 512);
        }
    };

    stage(0);
    for (int kt = 0; kt < SEQ / 64; ++kt) {
        __syncthreads();                     // tile kt ready (vmcnt drained)
        if (kt < SEQ / 64 - 1) stage(kt + 1);
        const int po = (kt & 1) * 4096;

        // ---- S^T = K Q^T (Q pre-scaled by log2e/8) : lane=q, regs=keys ----
        f32x16 accS[2] = {};
        #pragma unroll
        for (int kg = 0; kg < 2; ++kg)
            #pragma unroll
            for (int ks = 0; ks < 4; ++ks) {
                const bfrag kh_ = *(const bfrag*)&sKh[po + koff[kg][ks]];
                const bfrag kl_ = *(const bfrag*)&sKl[po + koff[kg][ks]];
                accS[kg] = __builtin_amdgcn_mfma_f32_32x32x16_bf16(kh_, qfh[ks], accS[kg], 0, 0, 0);
                accS[kg] = __builtin_amdgcn_mfma_f32_32x32x16_bf16(kh_, qfl[ks], accS[kg], 0, 0, 0);
                accS[kg] = __builtin_amdgcn_mfma_f32_32x32x16_bf16(kl_, qfh[ks], accS[kg], 0, 0, 0);
            }

        // ---- p = exp2(s') in registers (lane=q, reg=key) ----
        float pv[2][16];
        #pragma unroll
        for (int kg = 0; kg < 2; ++kg)
            #pragma unroll
            for (int r = 0; r < 16; ++r) {
                const float p = fexp2(accS[kg][r]);
                pv[kg][r] = p;
                l_loc += p;
            }

        // ---- O^T += Vh^T P^T (no exchange: permuted V^T; hi-only) ----
        #pragma unroll
        for (int kp = 0; kp < 4; ++kp) {
            const int kg = kp >> 1;
            const int t8 = (kp & 1) * 8;
            fragu ph;
            #pragma unroll
            for (int j2 = 0; j2 < 4; ++j2)
                ph.u[j2] = pk2bf(pv[kg][t8 + 2 * j2], pv[kg][t8 + 2 * j2 + 1]);
            #pragma unroll
            for (int dt = 0; dt < 2; ++dt) {
                const bfrag vh = *(const bfrag*)&sVh[po + koff[dt][kp]];
                accO[dt] = __builtin_amdgcn_mfma_f32_32x32x16_bf16(vh, ph.f, accO[dt], 0, 0, 0);
            }
        }
    }

    // ---- l: combine complementary g-halves; write BLOCKED hi/lo output ----
    const float inv = 1.0f / (l_loc + __shfl_xor(l_loc, 32));

    const int b = bh >> 4;
    const int h = bh & 15;
    const int sg = qt * 128 + w * 32 + l31;
    const int rm = sg * BATCH + b;                 // output row (0..4095)
    #pragma unroll
    for (int dt = 0; dt < 2; ++dt)
        #pragma unroll
        for (int rq = 0; rq < 4; ++rq) {
            const int j0 = 8 * rq + 4 * g;         // pos within 32-group
            const int t  = h * 2 + dt;             // group index
            __align__(8) u16 hb[4];
            __align__(8) u16 lb[4];
            #pragma unroll
            for (int i2 = 0; i2 < 4; ++i2) {
                const float v = accO[dt][rq * 4 + i2] * inv;
                const u32 hh = f2bf(v);
                hb[i2] = (u16)hh;
                lb[i2] = (u16)f2bf(v - bf2f(hh));
            }
            u16* o = AOb + (size_t)rm * 2048 + t * 64 + j0;
            *(uint2*)o        = *(const uint2*)hb;
            *(uint2*)(o + 32) = *(const uint2*)lb;
        }
}

// ---------------------------------------------------------------------------
extern "C" void kernel_launch(void* const* d_in, const int* in_sizes, int n_in,
                              void* d_out, int out_size, void* d_ws, size_t ws_size,
                              hipStream_t stream)
{
    float* query = (float*)d_in[0];       // packed in place by prep
    float* key   = (float*)d_in[1];
    float* value = (float*)d_in[2];
    const float* Wq    = (const float*)d_in[3];
    const float* bq    = (const float*)d_in[4];
    const float* Wk    = (const float*)d_in[5];
    const float* bk    = (const float*)d_in[6];
    const float* Wv    = (const float*)d_in[7];
    const float* bv    = (const float*)d_in[8];
    const float* Wo    = (const float*)d_in[9];
    const float* bo    = (const float*)d_in[10];
    float* out = (float*)d_out;

    // 64 MB workspace, time-multiplexed (MB offsets):
    //  Wqb [0,4) Wkb [4,8) Wvb [8,12) tab [12,12.5)  -- dead after qkv
    //  Qh [16,24) Ql [24,32) Kh [32,40) Kl [40,48) VTh [48,56)
    //  Wob [56,60)          (written in prep, read by out_gemm — never aliased)
    //  AOb blocked [0,16)   (W-packs + tab dead after qkv)
    char* wsb = (char*)d_ws;
    const size_t MB = 1024 * 1024;
    u16* Wqb = (u16*)(wsb + 0 * MB);
    u16* Wkb = (u16*)(wsb + 4 * MB);
    u16* Wvb = (u16*)(wsb + 8 * MB);
    float2* tab = (float2*)(wsb + 12 * MB);
    u16* Qh  = (u16*)(wsb + 16 * MB); u16* Ql  = (u16*)(wsb + 24 * MB);
    u16* Kh  = (u16*)(wsb + 32 * MB); u16* Kl  = (u16*)(wsb + 40 * MB);
    u16* VTh = (u16*)(wsb + 48 * MB);
    u16* Wob = (u16*)(wsb + 56 * MB);
    u16* AOb = (u16*)(wsb + 0 * MB);

    // pack weights (incl. Wo) + inputs (in place, blocked) + RoPE table
    prep_kernel<<<dim3(512, 8), 256, 0, stream>>>(
        Wq, Wk, Wv, Wo, query, key, value, Wqb, Wkb, Wvb, Wob, tab);
    // merged Q/K/V projections (+RoPE for Q/K; Q pre-scaled; V writes V^T hi)
    qkv_gemm_kernel<<<dim3(16, 32, 3), 256, 0, stream>>>(
        (const u16*)query, (const u16*)key, (const u16*)value,
        Wqb, Wkb, Wvb, bq, bk, bv, tab, Qh, Ql, Kh, Kl, VTh);
    // attention -> blocked hi/lo (S,B,D)
    attn_mfma_kernel<<<dim3(16, 32), 256, 0, stream>>>(
        Qh, Ql, Kh, Kl, VTh, AOb);
    // output projection
    out_gemm_kernel<<<dim3(32, 32), 256, 0, stream>>>(AOb, Wob, bo, out);
}